// Round 6
// baseline (76.665 us; speedup 1.0000x reference)
//
#include <hip/hip_runtime.h>

#define C0   8192
#define C1   2048
#define CE1  32768
#define CE2  2048
#define CBK  32      // per-scan-block e2 capacity
#define SL1  32      // LDS S1 slot cap (n1 ~ 13 expected)

struct KP {
  const float* x; const int* ei;
  const float* W0; const float* a1_0; const float* a2_0; const float* b0; const float* Wr0;
  const float* Wf; const float* a1f; const float* a2f; const float* bf;
  const float* Wfc; const float* bfc;
  float* out;
  int N, E, t, nb1, nscan;
  int* cnt;     // [1]=ne1 [2]=ne2 [3]=n0 [4]=n1 [6]=done
  float* wa;    // wa1[0..6], wa2[8..14]
  int* idx0; int* idx1; int* list0; int* list1;
  float* s0; float* acc0;
  int* e1s; int* e1d; int* e2s;
  int* cntblk; int* e2blk;
  float* f0; float* hh0; float* av10; float* av20;
};

__device__ __forceinline__ float lrelu(float v, float a){ return v >= 0.f ? v : a*v; }
__device__ __forceinline__ float selu_f(float v){
  const float sc = 1.0507009873554805f, al = 1.6732632423543772f;
  return v > 0.f ? sc*v : sc*al*expm1f(v);
}
// claim node into S0; zero its denom + 128-wide acc0 slot lazily
__device__ __forceinline__ void claim0(int* idx, int* list, int* cnt, int node,
                                       float* s, float* acc){
  if (atomicCAS(&idx[node], -1, -2) == -1){
    int slot = atomicAdd(cnt, 1);
    if (slot < C0){
      list[slot] = node;
      s[slot] = 0.f;
      float4* a = (float4*)(acc + (size_t)slot * 128);
      #pragma unroll
      for (int k = 0; k < 32; ++k) a[k] = make_float4(0.f,0.f,0.f,0.f);
      idx[node] = slot;
    }
  }
}
// claim node into S1 (no global acc; acc1 lives in tail LDS)
__device__ __forceinline__ void claim1(int* idx, int* list, int* cnt, int node){
  if (atomicCAS(&idx[node], -1, -2) == -1){
    int slot = atomicAdd(cnt, 1);
    if (slot < C1){ list[slot] = node; idx[node] = slot; }
  }
}

// K1: dual-role — blocks [0,nb1) init; blocks [nb1,nb1+nscan) scan dst==t
__global__ void k_init_scan1(KP p){
  int tid = threadIdx.x;
  if ((int)blockIdx.x < p.nb1){
    int u = blockIdx.x*256 + tid;
    if (u < p.N){ int v = (u == p.t) ? 0 : -1; p.idx0[u] = v; p.idx1[u] = v; }
    if (blockIdx.x == 0){
      if (tid < 7){
        float sA = 0.f, sB = 0.f;
        for (int k = 0; k < 128; ++k){ float wv = p.W0[tid*128+k]; sA += wv*p.a1_0[k]; sB += wv*p.a2_0[k]; }
        p.wa[tid] = sA; p.wa[8+tid] = sB;
      }
      if (tid < 128) p.acc0[tid] = 0.f;               // slot 0 = node t
      else if (tid == 128){
        p.s0[0] = 0.f; p.list0[0] = p.t; p.list1[0] = p.t;
        p.cnt[1] = 0; p.cnt[2] = 0; p.cnt[3] = 1; p.cnt[4] = 1; p.cnt[6] = 0;
      }
    }
    return;
  }
  // scan role: per-block compact list of srcs with dst == t (no global counters)
  __shared__ int lcnt;
  __shared__ int lbuf[CBK];
  int sb = blockIdx.x - p.nb1;
  if (tid == 0) lcnt = 0;
  __syncthreads();
  int gt = sb*256 + tid;
  int nv = p.E >> 2;
  const int4* d4 = (const int4*)(p.ei + p.E);
  if (gt < nv){
    int4 dv = d4[gt];
    #pragma unroll
    for (int m = 0; m < 4; ++m){
      if ((&dv.x)[m] == p.t){
        int pos = atomicAdd(&lcnt, 1);
        if (pos < CBK) lbuf[pos] = p.ei[4*gt + m];
      }
    }
  }
  if (sb == p.nscan-1 && tid < (p.E & 3)){
    int i = nv*4 + tid;
    if (p.ei[p.E + i] == p.t){
      int pos = atomicAdd(&lcnt, 1);
      if (pos < CBK) lbuf[pos] = p.ei[i];
    }
  }
  __syncthreads();
  int m = min(lcnt, CBK);
  if (tid == 0) p.cntblk[sb] = m;
  if (tid < m)  p.e2blk[sb*CBK + tid] = lbuf[tid];
}

// K2: bitmap of S1 from per-block lists; block0 compacts e2 + claims; all scan edges -> e1, claim S0
__global__ void k_scan2(KP p){
  __shared__ int bm[2048];
  __shared__ int e2c;
  int tid = threadIdx.x;
  int bmw = (p.N + 31) >> 5;
  for (int i = tid; i < bmw; i += 256) bm[i] = 0;
  if (tid == 0) e2c = 0;
  __syncthreads();
  if (tid == 0) atomicOr(&bm[p.t>>5], 1 << (p.t & 31));
  for (int i = tid; i < p.nscan; i += 256){
    int c = min(p.cntblk[i], CBK);
    for (int j = 0; j < c; ++j){
      int s = p.e2blk[i*CBK + j];
      atomicOr(&bm[s>>5], 1 << (s & 31));
      if (blockIdx.x == 0){
        int slot = atomicAdd(&e2c, 1);
        if (slot < CE2) p.e2s[slot] = s;
        claim1(p.idx1, p.list1, &p.cnt[4], s);
        claim0(p.idx0, p.list0, &p.cnt[3], s, p.s0, p.acc0);
      }
    }
  }
  __syncthreads();
  if (blockIdx.x == 0 && tid == 0) p.cnt[2] = min(e2c, CE2);
  int gt = blockIdx.x*256 + tid;
  int nv = p.E >> 2;
  const int4* d4 = (const int4*)(p.ei + p.E);
  if (gt < nv){
    int4 dv = d4[gt];
    #pragma unroll
    for (int m = 0; m < 4; ++m){
      int dd = (&dv.x)[m];
      if ((bm[dd>>5] >> (dd & 31)) & 1){
        int s = p.ei[4*gt + m];
        int slot = atomicAdd(&p.cnt[1], 1);
        if (slot < CE1){ p.e1s[slot] = s; p.e1d[slot] = dd; }
        claim0(p.idx0, p.list0, &p.cnt[3], s, p.s0, p.acc0);
      }
    }
  }
  if (gt < (p.E & 3)){
    int i = nv*4 + gt;
    int dd = p.ei[p.E + i];
    if ((bm[dd>>5] >> (dd & 31)) & 1){
      int s = p.ei[i];
      int slot = atomicAdd(&p.cnt[1], 1);
      if (slot < CE1){ p.e1s[slot] = s; p.e1d[slot] = dd; }
      claim0(p.idx0, p.list0, &p.cnt[3], s, p.s0, p.acc0);
    }
  }
}

// K3: edges into S0 -> fused level-0 aggregation (wave-cooperative)
__global__ void k_scan3(KP p){
  __shared__ int bm[2048];
  int tid = threadIdx.x;
  int bmw = (p.N + 31) >> 5;
  for (int i = tid; i < bmw; i += 256) bm[i] = 0;
  __syncthreads();
  int n0 = min(p.cnt[3], C0);
  for (int i = tid; i < n0; i += 256){ int u = p.list0[i]; atomicOr(&bm[u>>5], 1 << (u & 31)); }
  __syncthreads();
  int gt = blockIdx.x*256 + tid;
  int lane = tid & 63;
  int nv = p.E >> 2;
  const int4* d4 = (const int4*)(p.ei + p.E);
  bool inb = gt < nv;
  int4 dv = make_int4(-1,-1,-1,-1);
  if (inb) dv = d4[gt];
  #pragma unroll
  for (int m = 0; m < 4; ++m){
    int dd = inb ? (&dv.x)[m] : -1;
    bool match = (dd >= 0) && ((bm[dd>>5] >> (dd & 31)) & 1);
    int sv = 0;
    if (match) sv = p.ei[4*gt + m];
    unsigned long long b = __ballot(match);
    while (b){
      int l = __ffsll((long long)b) - 1; b &= b - 1;
      int s = __shfl(sv, l), d = __shfl(dd, l);
      float f = 0.f;
      #pragma unroll
      for (int j = 0; j < 7; ++j) f += p.x[s*7+j]*p.wa[j] + p.x[d*7+j]*p.wa[8+j];
      float e = expf(lrelu(f, 0.2f));
      int id = p.idx0[d];
      if (id >= 0){
        float h0 = 0.f, h1 = 0.f;
        #pragma unroll
        for (int j = 0; j < 7; ++j){
          float xs = p.x[s*7+j];
          float2 w2 = *(const float2*)&p.W0[j*128 + 2*lane];
          h0 += xs*w2.x; h1 += xs*w2.y;
        }
        atomicAdd(&p.acc0[(size_t)id*128 + 2*lane    ], e*h0);
        atomicAdd(&p.acc0[(size_t)id*128 + 2*lane + 1], e*h1);
        if (lane == 0) atomicAdd(&p.s0[id], e);
      }
    }
  }
  if (gt < (p.E & 3)){
    int i = nv*4 + gt;
    int dd = p.ei[p.E + i];
    if ((bm[dd>>5] >> (dd & 31)) & 1){
      int s = p.ei[i];
      float f = 0.f;
      for (int j = 0; j < 7; ++j) f += p.x[s*7+j]*p.wa[j] + p.x[dd*7+j]*p.wa[8+j];
      float e = expf(lrelu(f, 0.2f));
      int id = p.idx0[dd];
      if (id >= 0){
        for (int k = 0; k < 128; ++k){
          float h = 0.f;
          for (int j = 0; j < 7; ++j) h += p.x[s*7+j]*p.W0[j*128+k];
          atomicAdd(&p.acc0[(size_t)id*128 + k], e*h);
        }
        atomicAdd(&p.s0[id], e);
      }
    }
  }
}

// K4: fin0 (4 nodes/block, 512 thr) + last-block tail (agg1+fin1+l2, LDS-resident)
__global__ void __launch_bounds__(512) k_fin0_tail(KP p){
  __shared__ float  sf[4][128];
  __shared__ float2 rd2[4][128];
  int tid = threadIdx.x, sub = tid >> 7, ch = tid & 127;
  int n0 = min(p.cnt[3], C0);
  int stride = gridDim.x*4;
  for (int base = blockIdx.x*4; base < n0; base += stride){
    int b = base + sub; bool act = (b < n0);
    float v = 0.f, hv = 0.f;
    if (act){
      int u = p.list0[b];
      float res = 0.f;
      #pragma unroll
      for (int j = 0; j < 7; ++j) res += p.x[u*7+j]*p.Wr0[j*128+ch];
      v = selu_f(p.acc0[(size_t)b*128+ch]/(p.s0[b]+1e-9f) + p.b0[ch] + res);
      p.f0[(size_t)b*128+ch] = v;
      sf[sub][ch] = v;
    }
    __syncthreads();
    if (act){
      #pragma unroll 8
      for (int j = 0; j < 128; ++j) hv += sf[sub][j]*p.Wf[j*128+ch];
      p.hh0[(size_t)b*128+ch] = hv;
      rd2[sub][ch] = make_float2(hv*p.a1f[ch], hv*p.a2f[ch]);
    } else rd2[sub][ch] = make_float2(0.f, 0.f);
    __syncthreads();
    for (int st = 64; st > 0; st >>= 1){
      if (ch < st){ rd2[sub][ch].x += rd2[sub][ch+st].x; rd2[sub][ch].y += rd2[sub][ch+st].y; }
      __syncthreads();
    }
    if (act && ch == 0){ p.av10[b] = rd2[sub][0].x; p.av20[b] = rd2[sub][0].y; }
    __syncthreads();
  }
  // last-block-done handoff
  __threadfence();
  __shared__ int lastf;
  if (tid == 0){ int d = atomicAdd(&p.cnt[6], 1); lastf = (d == (int)gridDim.x - 1) ? 1 : 0; }
  __syncthreads();
  if (!lastf) return;
  __threadfence();

  // ---- tail (one block): level-1 agg + fin1 + layer2 + fc, all LDS-resident ----
  __shared__ float acc1L[SL1][128];
  __shared__ float s1L[SL1];
  __shared__ float f1L[SL1][128];
  __shared__ float hh1L[SL1][128];
  __shared__ float av11L[SL1], av21L[SL1];
  __shared__ float ev[512];
  __shared__ int   eis[512], ei1[512];
  __shared__ float redl[128];
  for (int i = tid; i < SL1*128; i += 512) acc1L[i>>7][i&127] = 0.f;
  if (tid < SL1) s1L[tid] = 0.f;
  __syncthreads();

  // Phase A: level-1 edge aggregation (stage wide, scatter float4 into LDS)
  int ne1 = min(p.cnt[1], CE1);
  for (int base = 0; base < ne1; base += 512){
    int i = base + tid;
    int i0s = -1, i1 = -1; float e = 0.f;
    if (i < ne1){
      int s = p.e1s[i], d = p.e1d[i];
      i0s = p.idx0[s]; int i0d = p.idx0[d]; i1 = p.idx1[d];
      if (i0s >= 0 && i0d >= 0 && i1 >= 0 && i1 < SL1){
        e = expf(lrelu(p.av10[i0s] + p.av20[i0d], 0.2f));
        atomicAdd(&s1L[i1], e);
      } else i0s = -1;
    }
    ev[tid] = e; eis[tid] = i0s; ei1[tid] = i1;
    __syncthreads();
    int c = min(512, ne1 - base);
    int total = c*32;
    for (int idx = tid; idx < total; idx += 512){
      int ee = idx >> 5, q = idx & 31;
      int s0i = eis[ee];
      if (s0i >= 0){
        float4 h = ((const float4*)(p.hh0 + (size_t)s0i*128))[q];
        float ee2 = ev[ee]; int i1e = ei1[ee];
        atomicAdd(&acc1L[i1e][q*4+0], ee2*h.x);
        atomicAdd(&acc1L[i1e][q*4+1], ee2*h.y);
        atomicAdd(&acc1L[i1e][q*4+2], ee2*h.z);
        atomicAdd(&acc1L[i1e][q*4+3], ee2*h.w);
      }
    }
    __syncthreads();
  }

  // Phase B: level-1 finalize + hh1 + av (4 nodes in parallel)
  int n1 = min(min(p.cnt[4], C1), SL1);
  for (int base = 0; base < n1; base += 4){
    int b = base + sub; bool act = (b < n1);
    float hv = 0.f;
    if (act){
      int u = p.list1[b]; int i0 = p.idx0[u];
      float f0v = (i0 >= 0) ? p.f0[(size_t)i0*128+ch] : 0.f;
      float lo = selu_f(acc1L[b][ch]/(s1L[b]+1e-9f) + p.bf[ch] + f0v);
      f1L[b][ch] = f0v + lo;
    }
    __syncthreads();
    if (act){
      #pragma unroll 8
      for (int j = 0; j < 128; ++j) hv += f1L[b][j]*p.Wf[16384 + j*128 + ch];
      hh1L[b][ch] = hv;
      rd2[sub][ch] = make_float2(hv*p.a1f[128+ch], hv*p.a2f[128+ch]);
    } else rd2[sub][ch] = make_float2(0.f, 0.f);
    __syncthreads();
    for (int st = 64; st > 0; st >>= 1){
      if (ch < st){ rd2[sub][ch].x += rd2[sub][ch+st].x; rd2[sub][ch].y += rd2[sub][ch+st].y; }
      __syncthreads();
    }
    if (act && ch == 0){ av11L[b] = rd2[sub][0].x; av21L[b] = rd2[sub][0].y; }
    __syncthreads();
  }

  // Phase C: layer-2 at t + fc + output
  int ne2 = min(p.cnt[2], CE2);
  float acc = 0.f, s2 = 0.f;
  for (int base = 0; base < ne2; base += 512){
    int i = base + tid; float e = 0.f; int si = -1;
    if (i < ne2){
      si = p.idx1[p.e2s[i]];
      if (si >= 0 && si < SL1) e = expf(lrelu(av11L[si] + av21L[0], 0.2f)); else si = -1;
    }
    ev[tid] = e; eis[tid] = si;
    __syncthreads();
    int c = min(512, ne2 - base);
    if (tid < 128){
      for (int q = 0; q < c; ++q){
        if (eis[q] >= 0){ s2 += ev[q]; acc += ev[q]*hh1L[eis[q]][tid]; }
      }
    }
    __syncthreads();
  }
  if (tid < 128){
    float f1v = f1L[0][tid];                 // slot 0 == node t
    float lo = selu_f(acc/(s2+1e-9f) + p.bf[128+tid] + f1v);
    redl[tid] = (f1v + lo)*p.Wfc[tid];
  }
  __syncthreads();
  for (int st = 64; st > 0; st >>= 1){
    if (tid < st) redl[tid] += redl[tid+st];
    __syncthreads();
  }
  if (tid == 0) p.out[0] = lrelu(redl[0] + p.bfc[0], 0.01f);
}

extern "C" void kernel_launch(void* const* d_in, const int* in_sizes, int n_in,
                              void* d_out, int out_size, void* d_ws, size_t ws_size,
                              hipStream_t stream){
  (void)n_in; (void)out_size;
  KP p;
  p.x    = (const float*)d_in[0];
  p.ei   = (const int*)  d_in[1];
  p.W0   = (const float*)d_in[2];
  p.a1_0 = (const float*)d_in[3];
  p.a2_0 = (const float*)d_in[4];
  p.b0   = (const float*)d_in[5];
  p.Wr0  = (const float*)d_in[6];
  // d_in[7..9] (Wa0,ba0,ua0) unused: SimpleAtt over T=1 is identity
  p.Wf   = (const float*)d_in[10];
  p.a1f  = (const float*)d_in[11];
  p.a2f  = (const float*)d_in[12];
  p.bf   = (const float*)d_in[13];
  // d_in[14..16] (Waf,baf,uaf) unused: identity
  p.Wfc  = (const float*)d_in[17];
  p.bfc  = (const float*)d_in[18];
  p.out  = (float*)d_out;

  p.N = in_sizes[0] / 7;
  p.E = in_sizes[1] / 2;
  p.t = p.N - 1;
  p.nb1   = (p.N + 255) / 256;
  p.nscan = ((p.E >> 2) + 255) / 256;

  char* q = (char*)d_ws;
  auto alloc = [&](size_t bytes) -> void* {
    void* r = (void*)q;
    q += (bytes + 255) & ~(size_t)255;
    return r;
  };
  p.cnt   = (int*)  alloc(64);
  p.wa    = (float*)alloc(sizeof(float)*16);
  p.idx0  = (int*)  alloc(sizeof(int)*(size_t)p.N);
  p.idx1  = (int*)  alloc(sizeof(int)*(size_t)p.N);
  p.list0 = (int*)  alloc(sizeof(int)*C0);
  p.list1 = (int*)  alloc(sizeof(int)*C1);
  p.s0    = (float*)alloc(sizeof(float)*C0);
  p.acc0  = (float*)alloc(sizeof(float)*(size_t)C0*128);
  p.e1s   = (int*)  alloc(sizeof(int)*CE1);
  p.e1d   = (int*)  alloc(sizeof(int)*CE1);
  p.e2s   = (int*)  alloc(sizeof(int)*CE2);
  p.cntblk= (int*)  alloc(sizeof(int)*(size_t)p.nscan);
  p.e2blk = (int*)  alloc(sizeof(int)*(size_t)p.nscan*CBK);
  p.f0    = (float*)alloc(sizeof(float)*(size_t)C0*128);
  p.hh0   = (float*)alloc(sizeof(float)*(size_t)C0*128);
  p.av10  = (float*)alloc(sizeof(float)*C0);
  p.av20  = (float*)alloc(sizeof(float)*C0);
  if ((size_t)(q - (char*)d_ws) > ws_size) return;  // ~13 MB needed

  k_init_scan1<<<p.nb1 + p.nscan, 256, 0, stream>>>(p);
  k_scan2     <<<p.nscan,         256, 0, stream>>>(p);
  k_scan3     <<<p.nscan,         256, 0, stream>>>(p);
  k_fin0_tail <<<64,              512, 0, stream>>>(p);
}

// Round 7
// 48.512 us; speedup vs baseline: 1.5803x; 1.5803x over previous
//
#include <hip/hip_runtime.h>

#define C0   8192
#define C1   2048
#define CE1  32768
#define CE2  2048
#define CBK  32      // per-scan-block e2 capacity

struct KP {
  const float* x; const int* ei;
  const float* W0; const float* a1_0; const float* a2_0; const float* b0; const float* Wr0;
  const float* Wf; const float* a1f; const float* a2f; const float* bf;
  const float* Wfc; const float* bfc;
  float* out;
  int N, E, t, nb1, nscan;
  int* cnt;     // [1]=ne1 [2]=ne2 [3]=n0 [4]=n1 [7]=done(fin1)
  float* wa;    // wa1[0..6], wa2[8..14]
  int* idx0; int* idx1; int* list0; int* list1;
  float* s0; float* acc0; float* s1; float* acc1;
  int* e1s; int* e1d; int* e2s;
  int* cntblk; int* e2blk;
  float* f0; float* hh0; float* av10; float* av20;
  float* f1; float* hh1; float* av11; float* av21;
};

__device__ __forceinline__ float lrelu(float v, float a){ return v >= 0.f ? v : a*v; }
__device__ __forceinline__ float selu_f(float v){
  const float sc = 1.0507009873554805f, al = 1.6732632423543772f;
  return v > 0.f ? sc*v : sc*al*expm1f(v);
}
// claim node into compact set; zero its denom + 128-wide accumulator slot
__device__ __forceinline__ void claimz(int* idx, int* list, int* cnt, int cap, int node,
                                       float* s, float* acc){
  if (atomicCAS(&idx[node], -1, -2) == -1){
    int slot = atomicAdd(cnt, 1);
    if (slot < cap){
      list[slot] = node;
      s[slot] = 0.f;
      float4* a = (float4*)(acc + (size_t)slot * 128);
      #pragma unroll
      for (int k = 0; k < 32; ++k) a[k] = make_float4(0.f,0.f,0.f,0.f);
      idx[node] = slot;
    }
  }
}

// K1: dual-role — blocks [0,nb1) init; blocks [nb1,nb1+nscan) scan dst==t
__global__ void k_init_scan1(KP p){
  int tid = threadIdx.x;
  if ((int)blockIdx.x < p.nb1){
    int u = blockIdx.x*256 + tid;
    if (u < p.N){ int v = (u == p.t) ? 0 : -1; p.idx0[u] = v; p.idx1[u] = v; }
    if (blockIdx.x == 0){
      if (tid < 7){
        float sA = 0.f, sB = 0.f;
        for (int k = 0; k < 128; ++k){ float wv = p.W0[tid*128+k]; sA += wv*p.a1_0[k]; sB += wv*p.a2_0[k]; }
        p.wa[tid] = sA; p.wa[8+tid] = sB;
      }
      if (tid < 128){ p.acc0[tid] = 0.f; p.acc1[tid] = 0.f; }   // slot 0 = node t
      else if (tid == 128){
        p.s0[0] = 0.f; p.s1[0] = 0.f; p.list0[0] = p.t; p.list1[0] = p.t;
        p.cnt[1] = 0; p.cnt[2] = 0; p.cnt[3] = 1; p.cnt[4] = 1; p.cnt[7] = 0;
      }
    }
    return;
  }
  // scan role: per-block compact list of srcs with dst == t (no global state needed)
  __shared__ int lcnt;
  __shared__ int lbuf[CBK];
  int sb = blockIdx.x - p.nb1;
  if (tid == 0) lcnt = 0;
  __syncthreads();
  int gt = sb*256 + tid;
  int nv = p.E >> 2;
  const int4* d4 = (const int4*)(p.ei + p.E);
  if (gt < nv){
    int4 dv = d4[gt];
    #pragma unroll
    for (int m = 0; m < 4; ++m){
      if ((&dv.x)[m] == p.t){
        int pos = atomicAdd(&lcnt, 1);
        if (pos < CBK) lbuf[pos] = p.ei[4*gt + m];
      }
    }
  }
  if (sb == p.nscan-1 && tid < (p.E & 3)){
    int i = nv*4 + tid;
    if (p.ei[p.E + i] == p.t){
      int pos = atomicAdd(&lcnt, 1);
      if (pos < CBK) lbuf[pos] = p.ei[i];
    }
  }
  __syncthreads();
  int m = min(lcnt, CBK);
  if (tid == 0) p.cntblk[sb] = m;
  if (tid < m)  p.e2blk[sb*CBK + tid] = lbuf[tid];
}

// K2: S1 bitmap from per-block lists; block0 compacts e2 + claims S1/S0; all blocks scan -> e1, claim S0
__global__ void k_scan2(KP p){
  __shared__ int bm[2048];
  __shared__ int e2c;
  int tid = threadIdx.x;
  int bmw = (p.N + 31) >> 5;
  for (int i = tid; i < bmw; i += 256) bm[i] = 0;
  if (tid == 0) e2c = 0;
  __syncthreads();
  if (tid == 0) atomicOr(&bm[p.t>>5], 1 << (p.t & 31));
  for (int i = tid; i < p.nscan; i += 256){
    int c = min(p.cntblk[i], CBK);
    for (int j = 0; j < c; ++j){
      int s = p.e2blk[i*CBK + j];
      atomicOr(&bm[s>>5], 1 << (s & 31));
      if (blockIdx.x == 0){
        int slot = atomicAdd(&e2c, 1);
        if (slot < CE2) p.e2s[slot] = s;
        claimz(p.idx1, p.list1, &p.cnt[4], C1, s, p.s1, p.acc1);
        claimz(p.idx0, p.list0, &p.cnt[3], C0, s, p.s0, p.acc0);
      }
    }
  }
  __syncthreads();
  if (blockIdx.x == 0 && tid == 0) p.cnt[2] = min(e2c, CE2);
  int gt = blockIdx.x*256 + tid;
  int nv = p.E >> 2;
  const int4* d4 = (const int4*)(p.ei + p.E);
  if (gt < nv){
    int4 dv = d4[gt];
    #pragma unroll
    for (int m = 0; m < 4; ++m){
      int dd = (&dv.x)[m];
      if ((bm[dd>>5] >> (dd & 31)) & 1){
        int s = p.ei[4*gt + m];
        int slot = atomicAdd(&p.cnt[1], 1);
        if (slot < CE1){ p.e1s[slot] = s; p.e1d[slot] = dd; }
        claimz(p.idx0, p.list0, &p.cnt[3], C0, s, p.s0, p.acc0);
      }
    }
  }
  if (gt < (p.E & 3)){
    int i = nv*4 + gt;
    int dd = p.ei[p.E + i];
    if ((bm[dd>>5] >> (dd & 31)) & 1){
      int s = p.ei[i];
      int slot = atomicAdd(&p.cnt[1], 1);
      if (slot < CE1){ p.e1s[slot] = s; p.e1d[slot] = dd; }
      claimz(p.idx0, p.list0, &p.cnt[3], C0, s, p.s0, p.acc0);
    }
  }
}

// K3: edges into S0 -> fused level-0 aggregation (wave-cooperative)
__global__ void k_scan3(KP p){
  __shared__ int bm[2048];
  int tid = threadIdx.x;
  int bmw = (p.N + 31) >> 5;
  for (int i = tid; i < bmw; i += 256) bm[i] = 0;
  __syncthreads();
  int n0 = min(p.cnt[3], C0);
  for (int i = tid; i < n0; i += 256){ int u = p.list0[i]; atomicOr(&bm[u>>5], 1 << (u & 31)); }
  __syncthreads();
  int gt = blockIdx.x*256 + tid;
  int lane = tid & 63;
  int nv = p.E >> 2;
  const int4* d4 = (const int4*)(p.ei + p.E);
  bool inb = gt < nv;
  int4 dv = make_int4(-1,-1,-1,-1);
  if (inb) dv = d4[gt];
  #pragma unroll
  for (int m = 0; m < 4; ++m){
    int dd = inb ? (&dv.x)[m] : -1;
    bool match = (dd >= 0) && ((bm[dd>>5] >> (dd & 31)) & 1);
    int sv = 0;
    if (match) sv = p.ei[4*gt + m];
    unsigned long long b = __ballot(match);
    while (b){
      int l = __ffsll((long long)b) - 1; b &= b - 1;
      int s = __shfl(sv, l), d = __shfl(dd, l);
      float f = 0.f;
      #pragma unroll
      for (int j = 0; j < 7; ++j) f += p.x[s*7+j]*p.wa[j] + p.x[d*7+j]*p.wa[8+j];
      float e = expf(lrelu(f, 0.2f));
      int id = p.idx0[d];
      if (id >= 0){
        float h0 = 0.f, h1 = 0.f;
        #pragma unroll
        for (int j = 0; j < 7; ++j){
          float xs = p.x[s*7+j];
          float2 w2 = *(const float2*)&p.W0[j*128 + 2*lane];
          h0 += xs*w2.x; h1 += xs*w2.y;
        }
        atomicAdd(&p.acc0[(size_t)id*128 + 2*lane    ], e*h0);
        atomicAdd(&p.acc0[(size_t)id*128 + 2*lane + 1], e*h1);
        if (lane == 0) atomicAdd(&p.s0[id], e);
      }
    }
  }
  if (gt < (p.E & 3)){
    int i = nv*4 + gt;
    int dd = p.ei[p.E + i];
    if ((bm[dd>>5] >> (dd & 31)) & 1){
      int s = p.ei[i];
      float f = 0.f;
      for (int j = 0; j < 7; ++j) f += p.x[s*7+j]*p.wa[j] + p.x[dd*7+j]*p.wa[8+j];
      float e = expf(lrelu(f, 0.2f));
      int id = p.idx0[dd];
      if (id >= 0){
        for (int k = 0; k < 128; ++k){
          float h = 0.f;
          for (int j = 0; j < 7; ++j) h += p.x[s*7+j]*p.W0[j*128+k];
          atomicAdd(&p.acc0[(size_t)id*128 + k], e*h);
        }
        atomicAdd(&p.s0[id], e);
      }
    }
  }
}

// K4: level-0 finalize + hh0 + av reductions (one node per block)
__global__ void __launch_bounds__(128) k_fin0(KP p){
  __shared__ float sf[128];
  __shared__ float2 red[128];
  int tid = threadIdx.x;
  int n0 = min(p.cnt[3], C0);
  for (int b = blockIdx.x; b < n0; b += gridDim.x){
    int u = p.list0[b];
    float res = 0.f;
    #pragma unroll
    for (int j = 0; j < 7; ++j) res += p.x[u*7+j]*p.Wr0[j*128+tid];
    float v = selu_f(p.acc0[(size_t)b*128+tid]/(p.s0[b]+1e-9f) + p.b0[tid] + res);
    p.f0[(size_t)b*128+tid] = v;
    sf[tid] = v;
    __syncthreads();
    float hv = 0.f;
    #pragma unroll 8
    for (int j = 0; j < 128; ++j) hv += sf[j]*p.Wf[j*128+tid];
    p.hh0[(size_t)b*128+tid] = hv;
    red[tid] = make_float2(hv*p.a1f[tid], hv*p.a2f[tid]);
    __syncthreads();
    for (int st = 64; st > 0; st >>= 1){
      if (tid < st){ red[tid].x += red[tid+st].x; red[tid].y += red[tid+st].y; }
      __syncthreads();
    }
    if (tid == 0){ p.av10[b] = red[0].x; p.av20[b] = red[0].y; }
    __syncthreads();
  }
}

// K5: level-1 edge aggregation, wave-per-edge (global atomics into acc1/s1)
__global__ void k_agg1(KP p){
  int gtid = blockIdx.x*blockDim.x + threadIdx.x;
  int wv = gtid >> 6, lane = gtid & 63;
  int nw = (gridDim.x*blockDim.x) >> 6;
  int ne1 = min(p.cnt[1], CE1);
  for (int i = wv; i < ne1; i += nw){
    int s = p.e1s[i], d = p.e1d[i];
    int i0s = p.idx0[s], i0d = p.idx0[d], i1 = p.idx1[d];
    if (i0s < 0 || i1 < 0 || i0d < 0) continue;
    float e = expf(lrelu(p.av10[i0s] + p.av20[i0d], 0.2f));
    float2 hv = *(const float2*)&p.hh0[(size_t)i0s*128 + 2*lane];
    atomicAdd(&p.acc1[(size_t)i1*128 + 2*lane    ], e*hv.x);
    atomicAdd(&p.acc1[(size_t)i1*128 + 2*lane + 1], e*hv.y);
    if (lane == 0) atomicAdd(&p.s1[i1], e);
  }
}

// K6: level-1 finalize (multi-block) + last-block l2 tail (~10 KB reads)
__global__ void __launch_bounds__(128) k_fin1_l2(KP p){
  __shared__ float sf[128];
  __shared__ float2 rd2[128];
  int tid = threadIdx.x;
  int n1 = min(p.cnt[4], C1);
  for (int b = blockIdx.x; b < n1; b += gridDim.x){
    int u = p.list1[b];
    int i0 = p.idx0[u];
    float f0v = (i0 >= 0) ? p.f0[(size_t)i0*128+tid] : 0.f;
    float lo = selu_f(p.acc1[(size_t)b*128+tid]/(p.s1[b]+1e-9f) + p.bf[tid] + f0v);
    float v = f0v + lo;
    p.f1[(size_t)b*128+tid] = v;
    sf[tid] = v;
    __syncthreads();
    float hv = 0.f;
    #pragma unroll 8
    for (int j = 0; j < 128; ++j) hv += sf[j]*p.Wf[16384 + j*128+tid];
    p.hh1[(size_t)b*128+tid] = hv;
    rd2[tid] = make_float2(hv*p.a1f[128+tid], hv*p.a2f[128+tid]);
    __syncthreads();
    for (int st = 64; st > 0; st >>= 1){
      if (tid < st){ rd2[tid].x += rd2[tid+st].x; rd2[tid].y += rd2[tid+st].y; }
      __syncthreads();
    }
    if (tid == 0){ p.av11[b] = rd2[0].x; p.av21[b] = rd2[0].y; }
    __syncthreads();
  }
  // last-block-done handoff (tail reads only ~10 KB)
  __threadfence();
  __shared__ int lastf;
  if (tid == 0) lastf = (atomicAdd(&p.cnt[7], 1) == (int)gridDim.x - 1) ? 1 : 0;
  __syncthreads();
  if (!lastf) return;
  __threadfence();
  __shared__ float se[128];
  __shared__ int   si[128];
  __shared__ float redl[128];
  int ne2 = min(p.cnt[2], CE2);
  float av21t = p.av21[0];
  float acc = 0.f, s2 = 0.f;
  for (int base = 0; base < ne2; base += 128){
    int i = base + tid; float e = 0.f; int ii = -1;
    if (i < ne2){
      ii = p.idx1[p.e2s[i]];
      if (ii >= 0) e = expf(lrelu(p.av11[ii] + av21t, 0.2f));
    }
    se[tid] = e; si[tid] = ii;
    __syncthreads();
    int c = min(128, ne2 - base);
    for (int q = 0; q < c; ++q){
      if (si[q] >= 0){ s2 += se[q]; acc += se[q]*p.hh1[(size_t)si[q]*128 + tid]; }
    }
    __syncthreads();
  }
  float f1v = p.f1[tid];                      // slot 0 == node t
  float lo = selu_f(acc/(s2+1e-9f) + p.bf[128+tid] + f1v);
  redl[tid] = (f1v + lo)*p.Wfc[tid];
  __syncthreads();
  for (int st = 64; st > 0; st >>= 1){
    if (tid < st) redl[tid] += redl[tid+st];
    __syncthreads();
  }
  if (tid == 0) p.out[0] = lrelu(redl[0] + p.bfc[0], 0.01f);
}

extern "C" void kernel_launch(void* const* d_in, const int* in_sizes, int n_in,
                              void* d_out, int out_size, void* d_ws, size_t ws_size,
                              hipStream_t stream){
  (void)n_in; (void)out_size;
  KP p;
  p.x    = (const float*)d_in[0];
  p.ei   = (const int*)  d_in[1];
  p.W0   = (const float*)d_in[2];
  p.a1_0 = (const float*)d_in[3];
  p.a2_0 = (const float*)d_in[4];
  p.b0   = (const float*)d_in[5];
  p.Wr0  = (const float*)d_in[6];
  // d_in[7..9] (Wa0,ba0,ua0) unused: SimpleAtt over T=1 is identity
  p.Wf   = (const float*)d_in[10];
  p.a1f  = (const float*)d_in[11];
  p.a2f  = (const float*)d_in[12];
  p.bf   = (const float*)d_in[13];
  // d_in[14..16] (Waf,baf,uaf) unused: identity
  p.Wfc  = (const float*)d_in[17];
  p.bfc  = (const float*)d_in[18];
  p.out  = (float*)d_out;

  p.N = in_sizes[0] / 7;
  p.E = in_sizes[1] / 2;
  p.t = p.N - 1;
  p.nb1   = (p.N + 255) / 256;
  p.nscan = ((p.E >> 2) + 255) / 256;

  char* q = (char*)d_ws;
  auto alloc = [&](size_t bytes) -> void* {
    void* r = (void*)q;
    q += (bytes + 255) & ~(size_t)255;
    return r;
  };
  p.cnt   = (int*)  alloc(64);
  p.wa    = (float*)alloc(sizeof(float)*16);
  p.idx0  = (int*)  alloc(sizeof(int)*(size_t)p.N);
  p.idx1  = (int*)  alloc(sizeof(int)*(size_t)p.N);
  p.list0 = (int*)  alloc(sizeof(int)*C0);
  p.list1 = (int*)  alloc(sizeof(int)*C1);
  p.s0    = (float*)alloc(sizeof(float)*C0);
  p.acc0  = (float*)alloc(sizeof(float)*(size_t)C0*128);
  p.s1    = (float*)alloc(sizeof(float)*C1);
  p.acc1  = (float*)alloc(sizeof(float)*(size_t)C1*128);
  p.e1s   = (int*)  alloc(sizeof(int)*CE1);
  p.e1d   = (int*)  alloc(sizeof(int)*CE1);
  p.e2s   = (int*)  alloc(sizeof(int)*CE2);
  p.cntblk= (int*)  alloc(sizeof(int)*(size_t)p.nscan);
  p.e2blk = (int*)  alloc(sizeof(int)*(size_t)p.nscan*CBK);
  p.f0    = (float*)alloc(sizeof(float)*(size_t)C0*128);
  p.hh0   = (float*)alloc(sizeof(float)*(size_t)C0*128);
  p.av10  = (float*)alloc(sizeof(float)*C0);
  p.av20  = (float*)alloc(sizeof(float)*C0);
  p.f1    = (float*)alloc(sizeof(float)*(size_t)C1*128);
  p.hh1   = (float*)alloc(sizeof(float)*(size_t)C1*128);
  p.av11  = (float*)alloc(sizeof(float)*C1);
  p.av21  = (float*)alloc(sizeof(float)*C1);
  if ((size_t)(q - (char*)d_ws) > ws_size) return;  // ~15 MB needed

  k_init_scan1<<<p.nb1 + p.nscan, 256, 0, stream>>>(p);
  k_scan2     <<<p.nscan,         256, 0, stream>>>(p);
  k_scan3     <<<p.nscan,         256, 0, stream>>>(p);
  k_fin0      <<<192,             128, 0, stream>>>(p);
  k_agg1      <<<64,              256, 0, stream>>>(p);
  k_fin1_l2   <<<32,              128, 0, stream>>>(p);
}

// Round 8
// 45.550 us; speedup vs baseline: 1.6831x; 1.0650x over previous
//
#include <hip/hip_runtime.h>

#define C0   8192
#define C1   2048
#define CE1  32768
#define CE2  2048
#define CBK  32      // per-scan-block e2 capacity
#define MB   1024    // per-node level-1 match buffer

struct KP {
  const float* x; const int* ei;
  const float* W0; const float* a1_0; const float* a2_0; const float* b0; const float* Wr0;
  const float* Wf; const float* a1f; const float* a2f; const float* bf;
  const float* Wfc; const float* bfc;
  float* out;
  int N, E, t, nb1, nscan;
  int* cnt;     // [1]=ne1 [2]=ne2 [3]=n0 [4]=n1 [7]=done(fin1)
  float* wa;    // wa1[0..6], wa2[8..14]
  int* idx0; int* idx1; int* list0; int* list1;
  float* s0; float* acc0;
  int* e1s; int* e1d; int* e2s;
  int* cntblk; int* e2blk;
  float* f0; float* hh0; float* av10; float* av20;
  float* f1; float* hh1; float* av11; float* av21;
};

__device__ __forceinline__ float lrelu(float v, float a){ return v >= 0.f ? v : a*v; }
__device__ __forceinline__ float selu_f(float v){
  const float sc = 1.0507009873554805f, al = 1.6732632423543772f;
  return v > 0.f ? sc*v : sc*al*expm1f(v);
}
// claim node into S0; zero its denom + 128-wide acc0 slot (scatter target)
__device__ __forceinline__ void claim0(int* idx, int* list, int* cnt, int node,
                                       float* s, float* acc){
  if (atomicCAS(&idx[node], -1, -2) == -1){
    int slot = atomicAdd(cnt, 1);
    if (slot < C0){
      list[slot] = node;
      s[slot] = 0.f;
      float4* a = (float4*)(acc + (size_t)slot * 128);
      #pragma unroll
      for (int k = 0; k < 32; ++k) a[k] = make_float4(0.f,0.f,0.f,0.f);
      idx[node] = slot;
    }
  }
}
// claim node into S1 (gather-based level 1: no accumulator to zero)
__device__ __forceinline__ void claim1(int* idx, int* list, int* cnt, int node){
  if (atomicCAS(&idx[node], -1, -2) == -1){
    int slot = atomicAdd(cnt, 1);
    if (slot < C1){ list[slot] = node; idx[node] = slot; }
  }
}

// K1: dual-role — blocks [0,nb1) init; blocks [nb1,nb1+nscan) scan dst==t
__global__ void k_init_scan1(KP p){
  int tid = threadIdx.x;
  if ((int)blockIdx.x < p.nb1){
    int u = blockIdx.x*256 + tid;
    if (u < p.N){ int v = (u == p.t) ? 0 : -1; p.idx0[u] = v; p.idx1[u] = v; }
    if (blockIdx.x == 0){
      if (tid < 7){
        float sA = 0.f, sB = 0.f;
        for (int k = 0; k < 128; ++k){ float wv = p.W0[tid*128+k]; sA += wv*p.a1_0[k]; sB += wv*p.a2_0[k]; }
        p.wa[tid] = sA; p.wa[8+tid] = sB;
      }
      if (tid < 128) p.acc0[tid] = 0.f;   // slot 0 = node t
      else if (tid == 128){
        p.s0[0] = 0.f; p.list0[0] = p.t; p.list1[0] = p.t;
        p.cnt[1] = 0; p.cnt[2] = 0; p.cnt[3] = 1; p.cnt[4] = 1; p.cnt[7] = 0;
      }
    }
    return;
  }
  // scan role: per-block compact list of srcs with dst == t
  __shared__ int lcnt;
  __shared__ int lbuf[CBK];
  int sb = blockIdx.x - p.nb1;
  if (tid == 0) lcnt = 0;
  __syncthreads();
  int gt = sb*256 + tid;
  int nv = p.E >> 2;
  const int4* d4 = (const int4*)(p.ei + p.E);
  if (gt < nv){
    int4 dv = d4[gt];
    #pragma unroll
    for (int m = 0; m < 4; ++m){
      if ((&dv.x)[m] == p.t){
        int pos = atomicAdd(&lcnt, 1);
        if (pos < CBK) lbuf[pos] = p.ei[4*gt + m];
      }
    }
  }
  if (sb == p.nscan-1 && tid < (p.E & 3)){
    int i = nv*4 + tid;
    if (p.ei[p.E + i] == p.t){
      int pos = atomicAdd(&lcnt, 1);
      if (pos < CBK) lbuf[pos] = p.ei[i];
    }
  }
  __syncthreads();
  int m = min(lcnt, CBK);
  if (tid == 0) p.cntblk[sb] = m;
  if (tid < m)  p.e2blk[sb*CBK + tid] = lbuf[tid];
}

// K2: S1 bitmap from per-block lists; block0 compacts e2 + claims S1/S0; all blocks scan -> e1, claim S0
__global__ void k_scan2(KP p){
  __shared__ int bm[2048];
  __shared__ int e2c;
  int tid = threadIdx.x;
  int bmw = (p.N + 31) >> 5;
  for (int i = tid; i < bmw; i += 256) bm[i] = 0;
  if (tid == 0) e2c = 0;
  __syncthreads();
  if (tid == 0) atomicOr(&bm[p.t>>5], 1 << (p.t & 31));
  for (int i = tid; i < p.nscan; i += 256){
    int c = min(p.cntblk[i], CBK);
    for (int j = 0; j < c; ++j){
      int s = p.e2blk[i*CBK + j];
      atomicOr(&bm[s>>5], 1 << (s & 31));
      if (blockIdx.x == 0){
        int slot = atomicAdd(&e2c, 1);
        if (slot < CE2) p.e2s[slot] = s;
        claim1(p.idx1, p.list1, &p.cnt[4], s);
        claim0(p.idx0, p.list0, &p.cnt[3], s, p.s0, p.acc0);
      }
    }
  }
  __syncthreads();
  if (blockIdx.x == 0 && tid == 0) p.cnt[2] = min(e2c, CE2);
  int gt = blockIdx.x*256 + tid;
  int nv = p.E >> 2;
  const int4* d4 = (const int4*)(p.ei + p.E);
  if (gt < nv){
    int4 dv = d4[gt];
    #pragma unroll
    for (int m = 0; m < 4; ++m){
      int dd = (&dv.x)[m];
      if ((bm[dd>>5] >> (dd & 31)) & 1){
        int s = p.ei[4*gt + m];
        int slot = atomicAdd(&p.cnt[1], 1);
        if (slot < CE1){ p.e1s[slot] = s; p.e1d[slot] = dd; }
        claim0(p.idx0, p.list0, &p.cnt[3], s, p.s0, p.acc0);
      }
    }
  }
  if (gt < (p.E & 3)){
    int i = nv*4 + gt;
    int dd = p.ei[p.E + i];
    if ((bm[dd>>5] >> (dd & 31)) & 1){
      int s = p.ei[i];
      int slot = atomicAdd(&p.cnt[1], 1);
      if (slot < CE1){ p.e1s[slot] = s; p.e1d[slot] = dd; }
      claim0(p.idx0, p.list0, &p.cnt[3], s, p.s0, p.acc0);
    }
  }
}

// K3: edges into S0 -> fused level-0 aggregation (wave-cooperative)
__global__ void k_scan3(KP p){
  __shared__ int bm[2048];
  int tid = threadIdx.x;
  int bmw = (p.N + 31) >> 5;
  for (int i = tid; i < bmw; i += 256) bm[i] = 0;
  __syncthreads();
  int n0 = min(p.cnt[3], C0);
  for (int i = tid; i < n0; i += 256){ int u = p.list0[i]; atomicOr(&bm[u>>5], 1 << (u & 31)); }
  __syncthreads();
  int gt = blockIdx.x*256 + tid;
  int lane = tid & 63;
  int nv = p.E >> 2;
  const int4* d4 = (const int4*)(p.ei + p.E);
  bool inb = gt < nv;
  int4 dv = make_int4(-1,-1,-1,-1);
  if (inb) dv = d4[gt];
  #pragma unroll
  for (int m = 0; m < 4; ++m){
    int dd = inb ? (&dv.x)[m] : -1;
    bool match = (dd >= 0) && ((bm[dd>>5] >> (dd & 31)) & 1);
    int sv = 0;
    if (match) sv = p.ei[4*gt + m];
    unsigned long long b = __ballot(match);
    while (b){
      int l = __ffsll((long long)b) - 1; b &= b - 1;
      int s = __shfl(sv, l), d = __shfl(dd, l);
      float f = 0.f;
      #pragma unroll
      for (int j = 0; j < 7; ++j) f += p.x[s*7+j]*p.wa[j] + p.x[d*7+j]*p.wa[8+j];
      float e = expf(lrelu(f, 0.2f));
      int id = p.idx0[d];
      if (id >= 0){
        float h0 = 0.f, h1 = 0.f;
        #pragma unroll
        for (int j = 0; j < 7; ++j){
          float xs = p.x[s*7+j];
          float2 w2 = *(const float2*)&p.W0[j*128 + 2*lane];
          h0 += xs*w2.x; h1 += xs*w2.y;
        }
        atomicAdd(&p.acc0[(size_t)id*128 + 2*lane    ], e*h0);
        atomicAdd(&p.acc0[(size_t)id*128 + 2*lane + 1], e*h1);
        if (lane == 0) atomicAdd(&p.s0[id], e);
      }
    }
  }
  if (gt < (p.E & 3)){
    int i = nv*4 + gt;
    int dd = p.ei[p.E + i];
    if ((bm[dd>>5] >> (dd & 31)) & 1){
      int s = p.ei[i];
      float f = 0.f;
      for (int j = 0; j < 7; ++j) f += p.x[s*7+j]*p.wa[j] + p.x[dd*7+j]*p.wa[8+j];
      float e = expf(lrelu(f, 0.2f));
      int id = p.idx0[dd];
      if (id >= 0){
        for (int k = 0; k < 128; ++k){
          float h = 0.f;
          for (int j = 0; j < 7; ++j) h += p.x[s*7+j]*p.W0[j*128+k];
          atomicAdd(&p.acc0[(size_t)id*128 + k], e*h);
        }
        atomicAdd(&p.s0[id], e);
      }
    }
  }
}

// K4: level-0 finalize + hh0 + av reductions (one node per block)
__global__ void __launch_bounds__(128) k_fin0(KP p){
  __shared__ float sf[128];
  __shared__ float2 red[128];
  int tid = threadIdx.x;
  int n0 = min(p.cnt[3], C0);
  for (int b = blockIdx.x; b < n0; b += gridDim.x){
    int u = p.list0[b];
    float res = 0.f;
    #pragma unroll
    for (int j = 0; j < 7; ++j) res += p.x[u*7+j]*p.Wr0[j*128+tid];
    float v = selu_f(p.acc0[(size_t)b*128+tid]/(p.s0[b]+1e-9f) + p.b0[tid] + res);
    p.f0[(size_t)b*128+tid] = v;
    sf[tid] = v;
    __syncthreads();
    float hv = 0.f;
    #pragma unroll 8
    for (int j = 0; j < 128; ++j) hv += sf[j]*p.Wf[j*128+tid];
    p.hh0[(size_t)b*128+tid] = hv;
    red[tid] = make_float2(hv*p.a1f[tid], hv*p.a2f[tid]);
    __syncthreads();
    for (int st = 64; st > 0; st >>= 1){
      if (tid < st){ red[tid].x += red[tid+st].x; red[tid].y += red[tid+st].y; }
      __syncthreads();
    }
    if (tid == 0){ p.av10[b] = red[0].x; p.av20[b] = red[0].y; }
    __syncthreads();
  }
}

// K5: GATHER-based level-1 (per-node in-edge scan, no atomics/acc1) + last-block l2 tail
__global__ void __launch_bounds__(128) k_fin1_l2(KP p){
  __shared__ float sf[128];
  __shared__ float2 rd2[128];
  __shared__ int   msrc[MB];
  __shared__ float mev[MB];
  __shared__ int   mcnt;
  int tid = threadIdx.x;
  int n1  = min(p.cnt[4], C1);
  int ne1 = min(p.cnt[1], CE1);
  for (int b = blockIdx.x; b < n1; b += gridDim.x){
    int u = p.list1[b];
    int i0u = p.idx0[u];
    if (tid == 0) mcnt = 0;
    __syncthreads();
    float av2u = (i0u >= 0) ? p.av20[i0u] : 0.f;
    // collect this node's in-edges from the e1 list
    for (int i = tid; i < ne1; i += 128){
      if (p.e1d[i] == u){
        int i0s = p.idx0[p.e1s[i]];
        if (i0s >= 0){
          float e = expf(lrelu(p.av10[i0s] + av2u, 0.2f));
          int pos = atomicAdd(&mcnt, 1);
          if (pos < MB){ msrc[pos] = i0s; mev[pos] = e; }
        }
      }
    }
    __syncthreads();
    int mc = min(mcnt, MB);
    float acc = 0.f, s1 = 0.f;
    for (int q = 0; q < mc; ++q){
      s1  += mev[q];
      acc += mev[q]*p.hh0[(size_t)msrc[q]*128 + tid];
    }
    float f0v = (i0u >= 0) ? p.f0[(size_t)i0u*128 + tid] : 0.f;
    float lo = selu_f(acc/(s1 + 1e-9f) + p.bf[tid] + f0v);
    float v = f0v + lo;
    p.f1[(size_t)b*128 + tid] = v;
    sf[tid] = v;
    __syncthreads();
    float hv = 0.f;
    #pragma unroll 8
    for (int j = 0; j < 128; ++j) hv += sf[j]*p.Wf[16384 + j*128 + tid];
    p.hh1[(size_t)b*128 + tid] = hv;
    rd2[tid] = make_float2(hv*p.a1f[128+tid], hv*p.a2f[128+tid]);
    __syncthreads();
    for (int st = 64; st > 0; st >>= 1){
      if (tid < st){ rd2[tid].x += rd2[tid+st].x; rd2[tid].y += rd2[tid+st].y; }
      __syncthreads();
    }
    if (tid == 0){ p.av11[b] = rd2[0].x; p.av21[b] = rd2[0].y; }
    __syncthreads();
  }
  // last-block-done handoff (tail reads only ~10 KB)
  __threadfence();
  __shared__ int lastf;
  if (tid == 0) lastf = (atomicAdd(&p.cnt[7], 1) == (int)gridDim.x - 1) ? 1 : 0;
  __syncthreads();
  if (!lastf) return;
  __threadfence();
  __shared__ float se[128];
  __shared__ int   si[128];
  __shared__ float redl[128];
  int ne2 = min(p.cnt[2], CE2);
  float av21t = p.av21[0];
  float acc = 0.f, s2 = 0.f;
  for (int base = 0; base < ne2; base += 128){
    int i = base + tid; float e = 0.f; int ii = -1;
    if (i < ne2){
      ii = p.idx1[p.e2s[i]];
      if (ii >= 0) e = expf(lrelu(p.av11[ii] + av21t, 0.2f));
    }
    se[tid] = e; si[tid] = ii;
    __syncthreads();
    int c = min(128, ne2 - base);
    for (int q = 0; q < c; ++q){
      if (si[q] >= 0){ s2 += se[q]; acc += se[q]*p.hh1[(size_t)si[q]*128 + tid]; }
    }
    __syncthreads();
  }
  float f1v = p.f1[tid];                      // slot 0 == node t
  float lo = selu_f(acc/(s2+1e-9f) + p.bf[128+tid] + f1v);
  redl[tid] = (f1v + lo)*p.Wfc[tid];
  __syncthreads();
  for (int st = 64; st > 0; st >>= 1){
    if (tid < st) redl[tid] += redl[tid+st];
    __syncthreads();
  }
  if (tid == 0) p.out[0] = lrelu(redl[0] + p.bfc[0], 0.01f);
}

extern "C" void kernel_launch(void* const* d_in, const int* in_sizes, int n_in,
                              void* d_out, int out_size, void* d_ws, size_t ws_size,
                              hipStream_t stream){
  (void)n_in; (void)out_size;
  KP p;
  p.x    = (const float*)d_in[0];
  p.ei   = (const int*)  d_in[1];
  p.W0   = (const float*)d_in[2];
  p.a1_0 = (const float*)d_in[3];
  p.a2_0 = (const float*)d_in[4];
  p.b0   = (const float*)d_in[5];
  p.Wr0  = (const float*)d_in[6];
  // d_in[7..9] (Wa0,ba0,ua0) unused: SimpleAtt over T=1 is identity
  p.Wf   = (const float*)d_in[10];
  p.a1f  = (const float*)d_in[11];
  p.a2f  = (const float*)d_in[12];
  p.bf   = (const float*)d_in[13];
  // d_in[14..16] (Waf,baf,uaf) unused: identity
  p.Wfc  = (const float*)d_in[17];
  p.bfc  = (const float*)d_in[18];
  p.out  = (float*)d_out;

  p.N = in_sizes[0] / 7;
  p.E = in_sizes[1] / 2;
  p.t = p.N - 1;
  p.nb1   = (p.N + 255) / 256;
  p.nscan = ((p.E >> 2) + 255) / 256;

  char* q = (char*)d_ws;
  auto alloc = [&](size_t bytes) -> void* {
    void* r = (void*)q;
    q += (bytes + 255) & ~(size_t)255;
    return r;
  };
  p.cnt   = (int*)  alloc(64);
  p.wa    = (float*)alloc(sizeof(float)*16);
  p.idx0  = (int*)  alloc(sizeof(int)*(size_t)p.N);
  p.idx1  = (int*)  alloc(sizeof(int)*(size_t)p.N);
  p.list0 = (int*)  alloc(sizeof(int)*C0);
  p.list1 = (int*)  alloc(sizeof(int)*C1);
  p.s0    = (float*)alloc(sizeof(float)*C0);
  p.acc0  = (float*)alloc(sizeof(float)*(size_t)C0*128);
  p.e1s   = (int*)  alloc(sizeof(int)*CE1);
  p.e1d   = (int*)  alloc(sizeof(int)*CE1);
  p.e2s   = (int*)  alloc(sizeof(int)*CE2);
  p.cntblk= (int*)  alloc(sizeof(int)*(size_t)p.nscan);
  p.e2blk = (int*)  alloc(sizeof(int)*(size_t)p.nscan*CBK);
  p.f0    = (float*)alloc(sizeof(float)*(size_t)C0*128);
  p.hh0   = (float*)alloc(sizeof(float)*(size_t)C0*128);
  p.av10  = (float*)alloc(sizeof(float)*C0);
  p.av20  = (float*)alloc(sizeof(float)*C0);
  p.f1    = (float*)alloc(sizeof(float)*(size_t)C1*128);
  p.hh1   = (float*)alloc(sizeof(float)*(size_t)C1*128);
  p.av11  = (float*)alloc(sizeof(float)*C1);
  p.av21  = (float*)alloc(sizeof(float)*C1);
  if ((size_t)(q - (char*)d_ws) > ws_size) return;  // ~14 MB needed

  k_init_scan1<<<p.nb1 + p.nscan, 256, 0, stream>>>(p);
  k_scan2     <<<p.nscan,         256, 0, stream>>>(p);
  k_scan3     <<<p.nscan,         256, 0, stream>>>(p);
  k_fin0      <<<192,             128, 0, stream>>>(p);
  k_fin1_l2   <<<32,              128, 0, stream>>>(p);
}